// Round 2
// baseline (496.429 us; speedup 1.0000x reference)
//
#include <hip/hip_runtime.h>
#include <hip/hip_bf16.h>

#define N_    2
#define T_    7
#define C_    96
#define H_    96
#define W_    96
#define HW_   9216
#define HEAD_ 4
#define HD_   24
#define C3_   288
#define P_    32
#define QP_   97
#define CATP_ 292
#define NBLK_ (N_ * (HW_ / P_))          // 576
#define ELEMS_ (N_ * T_ * C_ * HW_)      // 12,386,304 per big tensor

typedef unsigned int u32;
typedef unsigned short u16;

__device__ __forceinline__ float bits2f(u32 b) {
    union { u32 u; float f; } x; x.u = b; return x.f;
}

template<bool BF16>
__device__ __forceinline__ float ld1(const void* p, int i) {
    if constexpr (BF16) return bits2f(((u32)((const u16*)p)[i]) << 16);
    else                return ((const float*)p)[i];
}

template<bool BF16>
__device__ __forceinline__ void ld4w(const void* p, int i, float w[4]) {
    if constexpr (BF16) {
        const uint2 u = ((const uint2*)p)[i >> 2];
        w[0] = bits2f(u.x << 16);
        w[1] = bits2f(u.x & 0xFFFF0000u);
        w[2] = bits2f(u.y << 16);
        w[3] = bits2f(u.y & 0xFFFF0000u);
    } else {
        const float4 v = *((const float4*)((const float*)p + i));
        w[0] = v.x; w[1] = v.y; w[2] = v.z; w[3] = v.w;
    }
}

template<bool BF16>
__device__ __forceinline__ void st1(void* p, int i, float v) {
    if constexpr (BF16) ((__hip_bfloat16*)p)[i] = __float2bfloat16(v);
    else                ((float*)p)[i] = v;
}

__device__ __forceinline__ void unpack8(uint4 u, float f[8]) {
    f[0] = bits2f(u.x << 16); f[1] = bits2f(u.x & 0xFFFF0000u);
    f[2] = bits2f(u.y << 16); f[3] = bits2f(u.y & 0xFFFF0000u);
    f[4] = bits2f(u.z << 16); f[5] = bits2f(u.z & 0xFFFF0000u);
    f[6] = bits2f(u.w << 16); f[7] = bits2f(u.w & 0xFFFF0000u);
}

// ---- dtype detector (bf16 vs f32) ----
__global__ void detect_dtype_kernel(const u32* __restrict__ w, int* __restrict__ flag) {
    u32 x = w[threadIdx.x];
    u32 f = x & 0x7FFFu;
    int inwin = (f >= 0x3A00u) && (f <= 0x4200u);
    unsigned long long m = __ballot(inwin);
    if (threadIdx.x == 0) flag[0] = (__popcll(m) >= 40) ? 1 : 0;
}

// ---- transpose (n,t,c,hw) -> (n,t,hw,c), bf16 only ----
// grid: 4 tensors * 14 (n*t) * 36 pixel-blocks = 2016; block 256 (1 thread = 1 pixel)
__global__ __launch_bounds__(256) void transpose_kernel(
    const u16* __restrict__ idxf, const u16* __restrict__ s1,
    const u16* __restrict__ s2, const u16* __restrict__ s3,
    u16* __restrict__ wsb, const int* __restrict__ flag)
{
    if (*flag == 0) return;
    int b = blockIdx.x;
    int tens = b / 504;            // 504 = 14*36
    int rem  = b - tens * 504;
    int bt   = rem / 36;           // n*t batch
    int pb   = rem - bt * 36;
    const u16* src = (tens == 0) ? idxf : (tens == 1) ? s1 : (tens == 2) ? s2 : s3;
    int p = pb * 256 + threadIdx.x;                 // 0..9215
    const u16* sp = src + (size_t)bt * (C_ * HW_) + p;
    u16* dp = wsb + (size_t)tens * ELEMS_ + ((size_t)bt * HW_ + p) * C_;
    #pragma unroll
    for (int v = 0; v < 12; ++v) {
        u32 a[8];
        #pragma unroll
        for (int j = 0; j < 8; ++j) a[j] = sp[(size_t)(8 * v + j) * HW_];
        uint4 u;
        u.x = a[0] | (a[1] << 16);
        u.y = a[2] | (a[3] << 16);
        u.z = a[4] | (a[5] << 16);
        u.w = a[6] | (a[7] << 16);
        ((uint4*)dp)[v] = u;
    }
}

// ---- optimized main kernel (bf16, transposed gathers) ----
__global__ __launch_bounds__(256) void traj_opt(
    const u16* __restrict__ curr, const u16* __restrict__ anchor,
    const u16* __restrict__ loc, const u16* __restrict__ pw,
    const u16* __restrict__ pbias, const u16* __restrict__ fw,
    const u16* __restrict__ fbias, __hip_bfloat16* __restrict__ outp,
    const u16* __restrict__ wsb, const int* __restrict__ flag)
{
    if (*flag == 0) return;

    __shared__ __align__(16) u16 s_k[2][P_][C_];       // 12288 B, double-buffered k tile
    __shared__ __align__(16) u16 s_cat[P_][C3_];       // 18432 B
    __shared__ __align__(16) union {
        u16 curr[C_ * P_];                              // 6144 B (ch-major, px contiguous)
        float mid[P_][100];                             // 12800 B
    } s_u;
    __shared__ int   s_lin[T_][P_];
    __shared__ float s_soft[P_][HEAD_];
    __shared__ int   s_bidx[P_][HEAD_];

    const int tid = threadIdx.x;
    const int b   = blockIdx.x;
    const int nn  = b / (HW_ / P_);
    const int p0  = (b - nn * (HW_ / P_)) * P_;

    const u16* wsT[4];
    wsT[0] = wsb;                       // index_feat transposed
    wsT[1] = wsb + (size_t)1 * ELEMS_;  // s1
    wsT[2] = wsb + (size_t)2 * ELEMS_;  // s2
    wsT[3] = wsb + (size_t)3 * ELEMS_;  // s3

    // ---- nearest-sample indices (exact reference f32 op sequence) ----
    if (tid < T_ * P_) {
        int t = tid / P_, pp = tid - t * P_;
        int p = p0 + pp;
        float x = bits2f(((u32)loc[(nn * 2 * T_ + 2 * t    ) * HW_ + p]) << 16);
        float y = bits2f(((u32)loc[(nn * 2 * T_ + 2 * t + 1) * HW_ + p]) << 16);
        float gx = 2.0f * x / 95.0f - 1.0f;
        float gy = 2.0f * y / 95.0f - 1.0f;
        float fx = (gx + 1.0f) * 0.5f * 95.0f;
        float fy = (gy + 1.0f) * 0.5f * 95.0f;
        float ix = rintf(fx), iy = rintf(fy);
        bool v = (ix >= 0.0f) && (ix <= 95.0f) && (iy >= 0.0f) && (iy <= 95.0f);
        s_lin[t][pp] = v ? ((int)iy * W_ + (int)ix) : -1;
    }
    // ---- load curr tile, vectorized: 96 ch x 32 px ----
    for (int i = tid; i < C_ * 4; i += 256) {
        int ch = i >> 2, v = i & 3;
        const uint4 u = *((const uint4*)(curr + (size_t)(nn * C_ + ch) * HW_ + p0 + 8 * v));
        *((uint4*)&s_u.curr[ch * P_ + 8 * v]) = u;
    }
    __syncthreads();

    // ---- per (pp,h) thread: extract q fragment, normalize over full c ----
    const int pp = tid >> 2;        // valid for tid < 128
    const int hh = tid & 3;
    float qreg[HD_];
    float best = -3.0e38f;
    int   bidx = 0;
    if (tid < 128) {
        float ssq = 0.f;
        #pragma unroll
        for (int j = 0; j < HD_; ++j) {
            float v = bits2f(((u32)s_u.curr[(hh * HD_ + j) * P_ + pp]) << 16);
            qreg[j] = v;
            ssq += v * v;
        }
        ssq += __shfl_xor(ssq, 1);
        ssq += __shfl_xor(ssq, 2);
        float inv = 1.0f / fmaxf(sqrtf(ssq), 1e-12f);
        #pragma unroll
        for (int j = 0; j < HD_; ++j) qreg[j] *= inv;
    }

    // ---- k gather helper: 32 px * 12 uint4 per frame ----
    const u16* widx = wsT[0];
    auto gather_k = [&](int t, int buf) {
        for (int i = tid; i < P_ * 12; i += 256) {
            int gp = i / 12, v = i - gp * 12;
            int lin = s_lin[t][gp];
            uint4 u = make_uint4(0u, 0u, 0u, 0u);
            if (lin >= 0)
                u = *((const uint4*)(widx + ((size_t)(nn * T_ + t) * HW_ + lin) * C_ + 8 * v));
            *((uint4*)&s_k[buf][gp][8 * v]) = u;
        }
    };

    gather_k(0, 0);
    __syncthreads();
    for (int t = 0; t < T_; ++t) {
        if (t + 1 < T_) gather_k(t + 1, (t + 1) & 1);
        if (tid < 128) {
            const uint4* kp = (const uint4*)&s_k[t & 1][pp][hh * HD_];
            float kv[HD_];
            unpack8(kp[0], kv);
            unpack8(kp[1], kv + 8);
            unpack8(kp[2], kv + 16);
            float ssq = 0.f, dot = 0.f;
            #pragma unroll
            for (int j = 0; j < HD_; ++j) { ssq += kv[j] * kv[j]; dot += kv[j] * qreg[j]; }
            ssq += __shfl_xor(ssq, 1);
            ssq += __shfl_xor(ssq, 2);
            float score = dot * (1.0f / fmaxf(sqrtf(ssq), 1e-12f));
            if (score > best) { best = score; bidx = t; }   // strict > == first-max
        }
        __syncthreads();
    }
    if (tid < 128) { s_soft[pp][hh] = best; s_bidx[pp][hh] = bidx; }
    __syncthreads();

    // ---- gather winning frames into cat tile: 32 px * 36 uint4 ----
    for (int i = tid; i < P_ * 36; i += 256) {
        int gp = i / 36, chunk = i - gp * 36;
        int d0 = chunk * 8;
        int set = d0 / C_, ch = d0 - set * C_;
        int h = ch / HD_;
        int bt = s_bidx[gp][h];
        int lin = s_lin[bt][gp];
        uint4 u = make_uint4(0u, 0u, 0u, 0u);
        if (lin >= 0)
            u = *((const uint4*)(wsT[1 + set] + ((size_t)(nn * T_ + bt) * HW_ + lin) * C_ + ch));
        *((uint4*)&s_cat[gp][d0]) = u;
    }
    __syncthreads();

    // ---- fusion GEMV (96 x 288) + bias, scaled by per-head max score ----
    for (int u = tid; u < 24 * P_; u += 256) {
        int cog = u / P_, gp = u - cog * P_;
        int co0 = cog * 4;
        float a0 = 0.f, a1 = 0.f, a2 = 0.f, a3 = 0.f;
        for (int d = 0; d < C3_; d += 8) {
            float cv[8], wv[8];
            unpack8(*((const uint4*)&s_cat[gp][d]), cv);
            unpack8(*((const uint4*)(fw + (co0 + 0) * C3_ + d)), wv);
            #pragma unroll
            for (int j = 0; j < 8; ++j) a0 += wv[j] * cv[j];
            unpack8(*((const uint4*)(fw + (co0 + 1) * C3_ + d)), wv);
            #pragma unroll
            for (int j = 0; j < 8; ++j) a1 += wv[j] * cv[j];
            unpack8(*((const uint4*)(fw + (co0 + 2) * C3_ + d)), wv);
            #pragma unroll
            for (int j = 0; j < 8; ++j) a2 += wv[j] * cv[j];
            unpack8(*((const uint4*)(fw + (co0 + 3) * C3_ + d)), wv);
            #pragma unroll
            for (int j = 0; j < 8; ++j) a3 += wv[j] * cv[j];
        }
        float soft = s_soft[gp][co0 / HD_];
        s_u.mid[gp][co0 + 0] = (a0 + bits2f(((u32)fbias[co0 + 0]) << 16)) * soft;
        s_u.mid[gp][co0 + 1] = (a1 + bits2f(((u32)fbias[co0 + 1]) << 16)) * soft;
        s_u.mid[gp][co0 + 2] = (a2 + bits2f(((u32)fbias[co0 + 2]) << 16)) * soft;
        s_u.mid[gp][co0 + 3] = (a3 + bits2f(((u32)fbias[co0 + 3]) << 16)) * soft;
    }
    __syncthreads();

    // ---- proj GEMV (96 x 96) + bias + anchor, store ----
    for (int u = tid; u < 24 * P_; u += 256) {
        int dog = u / P_, gp = u - dog * P_;
        int do0 = dog * 4;
        float a0 = 0.f, a1 = 0.f, a2 = 0.f, a3 = 0.f;
        for (int c = 0; c < C_; c += 8) {
            const float4 m0 = *((const float4*)&s_u.mid[gp][c]);
            const float4 m1 = *((const float4*)&s_u.mid[gp][c + 4]);
            float mv[8] = { m0.x, m0.y, m0.z, m0.w, m1.x, m1.y, m1.z, m1.w };
            float wv[8];
            unpack8(*((const uint4*)(pw + (do0 + 0) * C_ + c)), wv);
            #pragma unroll
            for (int j = 0; j < 8; ++j) a0 += wv[j] * mv[j];
            unpack8(*((const uint4*)(pw + (do0 + 1) * C_ + c)), wv);
            #pragma unroll
            for (int j = 0; j < 8; ++j) a1 += wv[j] * mv[j];
            unpack8(*((const uint4*)(pw + (do0 + 2) * C_ + c)), wv);
            #pragma unroll
            for (int j = 0; j < 8; ++j) a2 += wv[j] * mv[j];
            unpack8(*((const uint4*)(pw + (do0 + 3) * C_ + c)), wv);
            #pragma unroll
            for (int j = 0; j < 8; ++j) a3 += wv[j] * mv[j];
        }
        int p = p0 + gp;
        #pragma unroll
        for (int r = 0; r < 4; ++r) {
            float* acc = (r == 0) ? &a0 : (r == 1) ? &a1 : (r == 2) ? &a2 : &a3;
            float res = *acc + bits2f(((u32)pbias[do0 + r]) << 16)
                      + bits2f(((u32)anchor[(size_t)(nn * C_ + do0 + r) * HW_ + p]) << 16);
            outp[(size_t)(nn * C_ + do0 + r) * HW_ + p] = __float2bfloat16(res);
        }
    }
}

// ================= round-1 fallback (works for both dtypes, no ws) =========
template<bool BF16>
__global__ __launch_bounds__(256) void traj_fallback(
    const void* __restrict__ curr, const void* __restrict__ idxf,
    const void* __restrict__ anchor, const void* __restrict__ s1,
    const void* __restrict__ s2, const void* __restrict__ s3,
    const void* __restrict__ loc, const void* __restrict__ pw,
    const void* __restrict__ pb, const void* __restrict__ fw,
    const void* __restrict__ fb, void* __restrict__ outp,
    const int* __restrict__ flag)
{
    if ((*flag != 0) != BF16) return;

    __shared__ __align__(16) float s_u[P_ * CATP_];
    __shared__ __align__(16) float s_mid[P_][100];
    __shared__ int   s_lin[T_][P_];
    __shared__ float s_red[P_][8];
    __shared__ float s_best[P_][HEAD_];
    __shared__ int   s_bidx[P_][HEAD_];
    __shared__ float s_inv[P_];

#define S_Q(pp, ch)  s_u[(pp) * QP_ + (ch)]
#define S_K(pp, ch)  s_u[3104 + (pp) * QP_ + (ch)]
#define S_CAT(pp, d) s_u[(pp) * CATP_ + (d)]

    const int tid = threadIdx.x;
    const int b  = blockIdx.x;
    const int nn = b / (HW_ / P_);
    const int p0 = (b - nn * (HW_ / P_)) * P_;

    if (tid < T_ * P_) {
        int t = tid / P_, pp = tid - t * P_;
        int p = p0 + pp;
        float x = ld1<BF16>(loc, (nn * 2 * T_ + 2 * t    ) * HW_ + p);
        float y = ld1<BF16>(loc, (nn * 2 * T_ + 2 * t + 1) * HW_ + p);
        float gx = 2.0f * x / 95.0f - 1.0f;
        float gy = 2.0f * y / 95.0f - 1.0f;
        float fx = (gx + 1.0f) * 0.5f * 95.0f;
        float fy = (gy + 1.0f) * 0.5f * 95.0f;
        float ix = rintf(fx), iy = rintf(fy);
        bool v = (ix >= 0.0f) && (ix <= 95.0f) && (iy >= 0.0f) && (iy <= 95.0f);
        s_lin[t][pp] = v ? ((int)iy * W_ + (int)ix) : -1;
    }
    if (tid < P_ * HEAD_) { s_best[tid >> 2][tid & 3] = -3.0e38f; s_bidx[tid >> 2][tid & 3] = 0; }

    for (int i = tid; i < C_ * P_; i += 256) {
        int ch = i / P_, pp = i - ch * P_;
        S_Q(pp, ch) = ld1<BF16>(curr, (nn * C_ + ch) * HW_ + p0 + pp);
    }
    __syncthreads();
    {
        int pp = tid >> 3, j = tid & 7;
        float s = 0.f;
        #pragma unroll
        for (int k = 0; k < 12; ++k) { float v = S_Q(pp, j * 12 + k); s += v * v; }
        s_red[pp][j] = s;
    }
    __syncthreads();
    if (tid < P_) {
        float s = 0.f;
        #pragma unroll
        for (int j = 0; j < 8; ++j) s += s_red[tid][j];
        s_inv[tid] = 1.0f / fmaxf(sqrtf(s), 1e-12f);
    }
    __syncthreads();
    for (int i = tid; i < C_ * P_; i += 256) {
        int ch = i / P_, pp = i - ch * P_;
        S_Q(pp, ch) *= s_inv[pp];
    }

    for (int t = 0; t < T_; ++t) {
        __syncthreads();
        for (int i = tid; i < C_ * P_; i += 256) {
            int ch = i / P_, pp = i - ch * P_;
            int lin = s_lin[t][pp];
            S_K(pp, ch) = (lin >= 0) ? ld1<BF16>(idxf, ((nn * T_ + t) * C_ + ch) * HW_ + lin) : 0.0f;
        }
        __syncthreads();
        {
            int pp = tid >> 3, j = tid & 7;
            float s = 0.f;
            #pragma unroll
            for (int k = 0; k < 12; ++k) { float v = S_K(pp, j * 12 + k); s += v * v; }
            s_red[pp][j] = s;
        }
        __syncthreads();
        if (tid < P_) {
            float s = 0.f;
            #pragma unroll
            for (int j = 0; j < 8; ++j) s += s_red[tid][j];
            s_inv[tid] = 1.0f / fmaxf(sqrtf(s), 1e-12f);
        }
        __syncthreads();
        if (tid < P_ * HEAD_) {
            int pp = tid >> 2, h = tid & 3;
            float s = 0.f;
            #pragma unroll
            for (int d = 0; d < HD_; ++d) s += S_K(pp, h * HD_ + d) * S_Q(pp, h * HD_ + d);
            s *= s_inv[pp];
            if (s > s_best[pp][h]) { s_best[pp][h] = s; s_bidx[pp][h] = t; }
        }
    }
    __syncthreads();

    for (int i = tid; i < C3_ * P_; i += 256) {
        int pp = i / C3_, d = i - pp * C3_;
        int set = d / C_, ch = d - set * C_;
        int h = ch / HD_;
        int bt = s_bidx[pp][h];
        int lin = s_lin[bt][pp];
        float v = 0.f;
        if (lin >= 0) {
            const void* sp = (set == 0) ? s1 : (set == 1) ? s2 : s3;
            v = ld1<BF16>(sp, ((nn * T_ + bt) * C_ + ch) * HW_ + lin);
        }
        S_CAT(pp, d) = v;
    }
    __syncthreads();

    for (int u = tid; u < 24 * P_; u += 256) {
        int cog = u / P_, pp = u - cog * P_;
        int co0 = cog * 4;
        float a0 = 0.f, a1 = 0.f, a2 = 0.f, a3 = 0.f;
        for (int d = 0; d < C3_; d += 4) {
            const float4 cv = *((const float4*)&S_CAT(pp, d));
            float w[4];
            ld4w<BF16>(fw, (co0 + 0) * C3_ + d, w);
            a0 += w[0] * cv.x + w[1] * cv.y + w[2] * cv.z + w[3] * cv.w;
            ld4w<BF16>(fw, (co0 + 1) * C3_ + d, w);
            a1 += w[0] * cv.x + w[1] * cv.y + w[2] * cv.z + w[3] * cv.w;
            ld4w<BF16>(fw, (co0 + 2) * C3_ + d, w);
            a2 += w[0] * cv.x + w[1] * cv.y + w[2] * cv.z + w[3] * cv.w;
            ld4w<BF16>(fw, (co0 + 3) * C3_ + d, w);
            a3 += w[0] * cv.x + w[1] * cv.y + w[2] * cv.z + w[3] * cv.w;
        }
        float soft = s_best[pp][co0 / HD_];
        s_mid[pp][co0 + 0] = (a0 + ld1<BF16>(fb, co0 + 0)) * soft;
        s_mid[pp][co0 + 1] = (a1 + ld1<BF16>(fb, co0 + 1)) * soft;
        s_mid[pp][co0 + 2] = (a2 + ld1<BF16>(fb, co0 + 2)) * soft;
        s_mid[pp][co0 + 3] = (a3 + ld1<BF16>(fb, co0 + 3)) * soft;
    }
    __syncthreads();

    for (int u = tid; u < 24 * P_; u += 256) {
        int dog = u / P_, pp = u - dog * P_;
        int do0 = dog * 4;
        float a0 = 0.f, a1 = 0.f, a2 = 0.f, a3 = 0.f;
        for (int c = 0; c < C_; c += 4) {
            const float4 mv = *((const float4*)&s_mid[pp][c]);
            float w[4];
            ld4w<BF16>(pw, (do0 + 0) * C_ + c, w);
            a0 += w[0] * mv.x + w[1] * mv.y + w[2] * mv.z + w[3] * mv.w;
            ld4w<BF16>(pw, (do0 + 1) * C_ + c, w);
            a1 += w[0] * mv.x + w[1] * mv.y + w[2] * mv.z + w[3] * mv.w;
            ld4w<BF16>(pw, (do0 + 2) * C_ + c, w);
            a2 += w[0] * mv.x + w[1] * mv.y + w[2] * mv.z + w[3] * mv.w;
            ld4w<BF16>(pw, (do0 + 3) * C_ + c, w);
            a3 += w[0] * mv.x + w[1] * mv.y + w[2] * mv.z + w[3] * mv.w;
        }
        int p = p0 + pp;
        float r0 = a0 + ld1<BF16>(pb, do0 + 0) + ld1<BF16>(anchor, (nn * C_ + do0 + 0) * HW_ + p);
        float r1 = a1 + ld1<BF16>(pb, do0 + 1) + ld1<BF16>(anchor, (nn * C_ + do0 + 1) * HW_ + p);
        float r2 = a2 + ld1<BF16>(pb, do0 + 2) + ld1<BF16>(anchor, (nn * C_ + do0 + 2) * HW_ + p);
        float r3 = a3 + ld1<BF16>(pb, do0 + 3) + ld1<BF16>(anchor, (nn * C_ + do0 + 3) * HW_ + p);
        st1<BF16>(outp, (nn * C_ + do0 + 0) * HW_ + p, r0);
        st1<BF16>(outp, (nn * C_ + do0 + 1) * HW_ + p, r1);
        st1<BF16>(outp, (nn * C_ + do0 + 2) * HW_ + p, r2);
        st1<BF16>(outp, (nn * C_ + do0 + 3) * HW_ + p, r3);
    }
#undef S_Q
#undef S_K
#undef S_CAT
}

extern "C" void kernel_launch(void* const* d_in, const int* in_sizes, int n_in,
                              void* d_out, int out_size, void* d_ws, size_t ws_size,
                              hipStream_t stream) {
    (void)in_sizes; (void)n_in; (void)out_size;
    int* flag = (int*)d_ws;
    u16* wsb = (u16*)((char*)d_ws + 16);
    detect_dtype_kernel<<<1, 64, 0, stream>>>((const u32*)d_in[0], flag);

    size_t need = 16 + (size_t)4 * ELEMS_ * 2;
    dim3 grid(NBLK_), block(256);
    if (ws_size >= need) {
        transpose_kernel<<<2016, 256, 0, stream>>>((const u16*)d_in[1], (const u16*)d_in[3],
                                                   (const u16*)d_in[4], (const u16*)d_in[5],
                                                   wsb, flag);
        traj_opt<<<grid, block, 0, stream>>>((const u16*)d_in[0], (const u16*)d_in[2],
                                             (const u16*)d_in[6], (const u16*)d_in[7],
                                             (const u16*)d_in[8], (const u16*)d_in[9],
                                             (const u16*)d_in[10], (__hip_bfloat16*)d_out,
                                             wsb, flag);
    } else {
        traj_fallback<true><<<grid, block, 0, stream>>>(d_in[0], d_in[1], d_in[2], d_in[3],
                                                        d_in[4], d_in[5], d_in[6], d_in[7],
                                                        d_in[8], d_in[9], d_in[10], d_out, flag);
    }
    traj_fallback<false><<<grid, block, 0, stream>>>(d_in[0], d_in[1], d_in[2], d_in[3],
                                                     d_in[4], d_in[5], d_in[6], d_in[7],
                                                     d_in[8], d_in[9], d_in[10], d_out, flag);
}